// Round 5
// baseline (31542.871 us; speedup 1.0000x reference)
//
#include <hip/hip_runtime.h>
#include <math.h>

// ---------------------------------------------------------------------------
// Helformer: sequential Holt-Winters scan (1 grid barrier/step via affine
// fold) + attention.  MI355X / gfx950.  B=4, S=1024, D=1024, H=16, HD=64, NS=12.
// ---------------------------------------------------------------------------

#define NBLK 256          // persistent scan grid (1 block / CU)
#define FLAG_STRIDE 16    // one 64B cache line per arrival flag (no false sharing)

// d_out layout (floats): output, attn, level_f, trend_f, hw_features
#define OUT_ATTN   4194304u
#define OUT_LEVEL  71303168u
#define OUT_TREND  71307264u
#define OUT_HW     71311360u

// workspace layout (floats)
#define WS_Q     0u
#define WS_K     4194304u
#define WS_V     8388608u
#define WS_CTX   12582912u
#define WS_LEVEL 16777216u                 // [2][4][1024]
#define WS_TREND (WS_LEVEL + 8192u)        // [2][4][1024]
#define WS_SBUF  (WS_TREND + 8192u)        // [12][1024]
#define WS_BTL   (WS_SBUF + 12288u)        // [1024]
#define WS_BSL   (WS_BTL + 1024u)          // [1024]
#define WS_FLAGS (WS_BSL + 1024u)          // NBLK*FLAG_STRIDE unsigned

__device__ __forceinline__ float dot4(float4 a, float4 b)
{
    return a.x * b.x + a.y * b.y + a.z * b.z + a.w * b.w;
}

// ---------------------------------------------------------------------------
// Software grid barrier, single-stage all-poll: each block stores its arrival
// flag (own 64B line), then thread i of EVERY block spins on flags[i].
// SIGNED-MONOTONE spin:
//   * ws poison 0xAAAAAAAA is negative as int  -> never false-releases;
//   * generations are small positives and only increase -> a block that runs
//     one generation ahead (max possible skew) still releases waiters that
//     sample late (an exact-equality spin can miss the window and deadlock).
// s_sleep(1) throttles poll traffic (65536 poll streams otherwise congest the
// fabric the arrival stores must cross); adds <=~30ns expected latency.
// Requires blockDim.x >= NBLK (256 == 256 here).
// ---------------------------------------------------------------------------
__device__ __forceinline__ void gbar(unsigned* flags, unsigned gen)
{
    __syncthreads();
    if (threadIdx.x == 0) {
        __threadfence();   // make this block's global writes visible device-wide
        __hip_atomic_store(&flags[blockIdx.x * FLAG_STRIDE], gen, __ATOMIC_RELEASE, __HIP_MEMORY_SCOPE_AGENT);
    }
    while ((int)__hip_atomic_load(&flags[threadIdx.x * FLAG_STRIDE], __ATOMIC_ACQUIRE, __HIP_MEMORY_SCOPE_AGENT) < (int)gen) {
        __builtin_amdgcn_s_sleep(1);
    }
    __syncthreads();
}

// ---------------------------------------------------------------------------
// Bias folds:  btl = sb*(Wt @ bl) + bt ;  bsl = -sg*(Ws @ bl) + bs
// ---------------------------------------------------------------------------
__global__ __launch_bounds__(256) void bias_fold(
    const float* __restrict__ Wt, const float* __restrict__ btv,
    const float* __restrict__ Wsw, const float* __restrict__ bsv,
    const float* __restrict__ blv,
    const float* __restrict__ pb, const float* __restrict__ pg,
    float* __restrict__ btl, float* __restrict__ bsl)
{
    const int w = threadIdx.x >> 6, lane = threadIdx.x & 63;
    const float sb_ = 1.f / (1.f + expf(-pb[0]));
    const float sg_ = 1.f / (1.f + expf(-pg[0]));
    float4 blr[4];
#pragma unroll
    for (int c = 0; c < 4; ++c) blr[c] = *(const float4*)&blv[c * 256 + lane * 4];
    for (int s = 0; s < 16; ++s) {
        const int o = blockIdx.x * 64 + w * 16 + s;
        float tacc = 0.f, sacc = 0.f;
#pragma unroll
        for (int c = 0; c < 4; ++c) {
            float4 wt4 = *(const float4*)&Wt[o * 1024 + c * 256 + lane * 4];
            float4 ws4 = *(const float4*)&Wsw[o * 1024 + c * 256 + lane * 4];
            tacc += dot4(wt4, blr[c]);
            sacc += dot4(ws4, blr[c]);
        }
#pragma unroll
        for (int m = 1; m < 64; m <<= 1) {
            tacc += __shfl_xor(tacc, m);
            sacc += __shfl_xor(sacc, m);
        }
        if (lane == 0) {
            btl[o] = sb_ * tacc + btv[o];
            bsl[o] = -sg_ * sacc + bsv[o];
        }
    }
}

// ---------------------------------------------------------------------------
// Weight-product precompute: M1 = Wt @ Wl, M2 = Ws @ Wl
// 64x64 tile, BK=32, 4x4/thread, k-major LDS.
// ---------------------------------------------------------------------------
__global__ __launch_bounds__(256, 2) void ww_gemm(
    const float* __restrict__ Wt, const float* __restrict__ Wsw,
    const float* __restrict__ Wl,
    float* __restrict__ M1, float* __restrict__ M2)
{
    const float* A = blockIdx.z ? Wsw : Wt;
    float*       C = blockIdx.z ? M2 : M1;
    const int m0 = blockIdx.x * 64, n0 = blockIdx.y * 64;
    const int tid = threadIdx.x, tx = tid & 15, ty = tid >> 4;
    __shared__ float As[32][68];
    __shared__ float Bs[32][68];
    float acc[4][4] = {};
    for (int k0 = 0; k0 < 1024; k0 += 32) {
#pragma unroll
        for (int i = 0; i < 2; ++i) {
            int f = tid + i * 256;
            int rA = f >> 3, cA = (f & 7) * 4;
            float4 a = *(const float4*)&A[(m0 + rA) * 1024 + k0 + cA];
            As[cA + 0][rA] = a.x; As[cA + 1][rA] = a.y;
            As[cA + 2][rA] = a.z; As[cA + 3][rA] = a.w;
            int rB = f >> 4, cB = (f & 15) * 4;
            *(float4*)&Bs[rB][cB] = *(const float4*)&Wl[(k0 + rB) * 1024 + n0 + cB];
        }
        __syncthreads();
#pragma unroll
        for (int kk = 0; kk < 32; ++kk) {
            float4 a = *(const float4*)&As[kk][ty * 4];
            float4 b = *(const float4*)&Bs[kk][tx * 4];
            acc[0][0] += a.x * b.x; acc[0][1] += a.x * b.y; acc[0][2] += a.x * b.z; acc[0][3] += a.x * b.w;
            acc[1][0] += a.y * b.x; acc[1][1] += a.y * b.y; acc[1][2] += a.y * b.z; acc[1][3] += a.y * b.w;
            acc[2][0] += a.z * b.x; acc[2][1] += a.z * b.y; acc[2][2] += a.z * b.z; acc[2][3] += a.z * b.w;
            acc[3][0] += a.w * b.x; acc[3][1] += a.w * b.y; acc[3][2] += a.w * b.z; acc[3][3] += a.w * b.w;
        }
        __syncthreads();
    }
#pragma unroll
    for (int i = 0; i < 4; ++i) {
        float4 v; v.x = acc[i][0]; v.y = acc[i][1]; v.z = acc[i][2]; v.w = acc[i][3];
        *(float4*)&C[(size_t)(m0 + ty * 4 + i) * 1024 + n0 + tx * 4] = v;
    }
}

// ---------------------------------------------------------------------------
// Persistent scan: 256 blocks x 256 threads, ONE grid barrier per timestep.
//   level_new = u1@Wl^T + bl
//   trend_new = sb*(u1@M1^T) + u2@Wt^T + btl         (M1 = Wt@Wl)
//   seas_upd  = u3@Ws^T   - sg*(u1@M2^T) + bsl       (M2 = Ws@Wl)
// with u1 = sa*(x-sc)+(1-sa)*(lev+trd), u2 = -sb*lev+(1-sb)*trd,
//      u3 = sg*x+(1-sg)*sc  -- all from step-start state.
// Weights register-resident (5 mats x 8 float4/lane, 32-lane k-slices).
// Wave w of block bid owns output column o = bid*4+w; 32-lane dots over
// batches {sub, sub+2}.  sc prefetched one step early (race-free: season
// index idx_t = t%12 never repeats on consecutive steps).
// ---------------------------------------------------------------------------
__global__ __launch_bounds__(256, 1) void scan_kernel(
    const float* __restrict__ x,          // [B,S,D]
    const int*   __restrict__ tidx,       // [B,S]
    const float* __restrict__ pa, const float* __restrict__ pb, const float* __restrict__ pg,
    const float* __restrict__ seas_init,  // [NS,D]
    const float* __restrict__ Wl, const float* __restrict__ blv,
    const float* __restrict__ Wt, const float* __restrict__ Wsw,
    const float* __restrict__ M1, const float* __restrict__ M2,
    const float* __restrict__ btl, const float* __restrict__ bsl,
    float* __restrict__ hw, float* __restrict__ level_f, float* __restrict__ trend_f,
    float* __restrict__ level_buf, float* __restrict__ trend_buf, float* __restrict__ sbuf,
    unsigned* __restrict__ flags)
{
    const int tid = threadIdx.x, bid = blockIdx.x;
    const int w = tid >> 6, lane = tid & 63;
    const int lj = lane & 31, sub = lane >> 5;
    const int o = (bid << 2) + w;
    const int c4 = tid * 4;

    __shared__ float u1[4][1024];
    __shared__ float u2[4][1024];
    __shared__ float u3[4][1024];

    const float sa_ = 1.f / (1.f + expf(-pa[0]));
    const float sb_ = 1.f / (1.f + expf(-pb[0]));
    const float sg_ = 1.f / (1.f + expf(-pg[0]));
    const float isa = 1.f - sa_, isb = 1.f - sb_, isg = 1.f - sg_;

    // register-resident weight rows (chunk c covers k in [c*128, c*128+128))
    float4 rWl[8], rWt[8], rWs[8], rM1[8], rM2[8];
#pragma unroll
    for (int c = 0; c < 8; ++c) {
        const int kk = c * 128 + lj * 4;
        rWl[c] = *(const float4*)&Wl [o * 1024 + kk];
        rWt[c] = *(const float4*)&Wt [o * 1024 + kk];
        rWs[c] = *(const float4*)&Wsw[o * 1024 + kk];
        float4 a = *(const float4*)&M1[o * 1024 + kk];
        a.x *= sb_; a.y *= sb_; a.z *= sb_; a.w *= sb_;
        rM1[c] = a;
        float4 b = *(const float4*)&M2[o * 1024 + kk];
        b.x *= -sg_; b.y *= -sg_; b.z *= -sg_; b.w *= -sg_;
        rM2[c] = b;
    }
    const float bl_o = blv[o], btl_o = btl[o], bsl_o = bsl[o];

    // init mutable state (ws poisoned before every launch)
    if (bid < 12) {
        for (int k = tid; k < 1024; k += 256) sbuf[bid * 1024 + k] = seas_init[bid * 1024 + k];
    } else if (bid < 16) {
        const int e0 = (bid - 12) * 1024;
        for (int k = tid; k < 1024; k += 256) { level_buf[e0 + k] = 0.f; trend_buf[e0 + k] = 0.f; }
    }

    unsigned gen = 1;
    gbar(flags, gen); gen++;

    // prefetch x(t=0) and sc(idx_0)
    float4 xv[4];
    float4 scv;
    {
        const int idx0 = ((tidx[0] + tidx[1024] + tidx[2048] + tidx[3072]) >> 2) % 12;
#pragma unroll
        for (int b = 0; b < 4; ++b) xv[b] = *(const float4*)&x[(size_t)(b * 1024 + 0) * 1024 + c4];
        scv = *(const float4*)&sbuf[idx0 * 1024 + c4];
    }

    int p = 0;
    for (int t = 0; t < 1024; ++t) {
        const int idx = ((tidx[t] + tidx[1024 + t] + tidx[2048 + t] + tidx[3072 + t]) >> 2) % 12;
        const float* lev = level_buf + p * 4096;
        const float* trd = trend_buf + p * 4096;
        float* levn = level_buf + (p ^ 1) * 4096;
        float* trdn = trend_buf + (p ^ 1) * 4096;

        // build u1/u2/u3 (this thread's 4 columns, all batches)
#pragma unroll
        for (int b = 0; b < 4; ++b) {
            float4 lv = *(const float4*)&lev[b * 1024 + c4];
            float4 tv = *(const float4*)&trd[b * 1024 + c4];
            float4 xb = xv[b];
            float4 a, bb, cc;
            a.x = sa_ * (xb.x - scv.x) + isa * (lv.x + tv.x);
            a.y = sa_ * (xb.y - scv.y) + isa * (lv.y + tv.y);
            a.z = sa_ * (xb.z - scv.z) + isa * (lv.z + tv.z);
            a.w = sa_ * (xb.w - scv.w) + isa * (lv.w + tv.w);
            bb.x = -sb_ * lv.x + isb * tv.x;  bb.y = -sb_ * lv.y + isb * tv.y;
            bb.z = -sb_ * lv.z + isb * tv.z;  bb.w = -sb_ * lv.w + isb * tv.w;
            cc.x = sg_ * xb.x + isg * scv.x;  cc.y = sg_ * xb.y + isg * scv.y;
            cc.z = sg_ * xb.z + isg * scv.z;  cc.w = sg_ * xb.w + isg * scv.w;
            *(float4*)&u1[b][c4] = a;
            *(float4*)&u2[b][c4] = bb;
            *(float4*)&u3[b][c4] = cc;
        }
        // prefetch next step's x and sc (sc row != this step's written row)
        if (t < 1023) {
            const int tn = t + 1;
            const int idxn = ((tidx[tn] + tidx[1024 + tn] + tidx[2048 + tn] + tidx[3072 + tn]) >> 2) % 12;
#pragma unroll
            for (int b = 0; b < 4; ++b) xv[b] = *(const float4*)&x[(size_t)(b * 1024 + tn) * 1024 + c4];
            scv = *(const float4*)&sbuf[idxn * 1024 + c4];
        }
        __syncthreads();

        // 32-lane dots; each lane covers batches {sub, sub+2}
        float smean = 0.f;
#pragma unroll
        for (int it = 0; it < 2; ++it) {
            const int b = it * 2 + sub;
            float aL = 0.f, aT = 0.f, aS = 0.f;
#pragma unroll
            for (int c = 0; c < 8; ++c) {
                const int kk = c * 128 + lj * 4;
                float4 a1 = *(const float4*)&u1[b][kk];
                float4 a2 = *(const float4*)&u2[b][kk];
                float4 a3 = *(const float4*)&u3[b][kk];
                aL += dot4(a1, rWl[c]);
                aT += dot4(a1, rM1[c]) + dot4(a2, rWt[c]);
                aS += dot4(a1, rM2[c]) + dot4(a3, rWs[c]);
            }
#pragma unroll
            for (int m = 1; m < 32; m <<= 1) {
                aL += __shfl_xor(aL, m);
                aT += __shfl_xor(aT, m);
                aS += __shfl_xor(aS, m);
            }
            const float ln = aL + bl_o, tn2 = aT + btl_o, sn = aS + bsl_o;
            if (lj == 0) {
                levn[b * 1024 + o] = ln;
                trdn[b * 1024 + o] = tn2;
                hw[(size_t)(b * 1024 + t) * 1024 + o] = ln + tn2 + sn;
                smean += sn;
            }
        }
        smean += __shfl_xor(smean, 32);
        if (lane == 0) sbuf[idx * 1024 + o] = 0.25f * smean;

        p ^= 1;
        gbar(flags, gen); gen++;
    }

    // final carries (p == 0 after 1024 flips)
    for (int e = bid * 256 + tid; e < 4096; e += NBLK * 256) {
        level_f[e] = level_buf[p * 4096 + e];
        trend_f[e] = trend_buf[p * 4096 + e];
    }
}

// ---------------------------------------------------------------------------
// Projection GEMM: out[m][n] = sum_k A[m][k]*W[n][k] + bias[n]
// MODE 0: A = hw + temporal_emb[tidx[m]%12]; out scattered to [B,H,S,HD]; z=Wq/Wk/Wv
// MODE 1: A = ctx; out -> [B,S,D]
// 128x128 tile, BK=16, 8x8/thread, k-major LDS (float4 inner reads).
// ---------------------------------------------------------------------------
template <int MODE>
__global__ __launch_bounds__(256, 2) void gemm_kernel(
    const float* __restrict__ Abase, const float* __restrict__ temb,
    const int* __restrict__ tidx,
    const float* __restrict__ W0, const float* __restrict__ b0v,
    const float* __restrict__ W1, const float* __restrict__ b1v,
    const float* __restrict__ W2, const float* __restrict__ b2v,
    float* __restrict__ o0, float* __restrict__ o1, float* __restrict__ o2)
{
    const int z = blockIdx.z;
    const float* W    = (z == 0) ? W0 : (z == 1) ? W1 : W2;
    const float* bias = (z == 0) ? b0v : (z == 1) ? b1v : b2v;
    float*       out  = (z == 0) ? o0 : (z == 1) ? o1 : o2;

    const int m0 = blockIdx.x * 128, n0 = blockIdx.y * 128;
    const int tid = threadIdx.x, tx = tid & 15, ty = tid >> 4;

    __shared__ float As[16][132];
    __shared__ float Bs[16][132];

    float acc[8][8] = {};

    for (int k0 = 0; k0 < 1024; k0 += 16) {
#pragma unroll
        for (int i = 0; i < 2; ++i) {
            int f = tid + i * 256;
            int r = f >> 2, cg = (f & 3) * 4;
            float4 a = *(const float4*)&Abase[(size_t)(m0 + r) * 1024 + k0 + cg];
            if (MODE == 0) {
                int er = (int)(((unsigned)tidx[m0 + r]) % 12u);
                float4 tv = *(const float4*)&temb[er * 1024 + k0 + cg];
                a.x += tv.x; a.y += tv.y; a.z += tv.z; a.w += tv.w;
            }
            As[cg + 0][r] = a.x; As[cg + 1][r] = a.y; As[cg + 2][r] = a.z; As[cg + 3][r] = a.w;
            float4 b = *(const float4*)&W[(size_t)(n0 + r) * 1024 + k0 + cg];
            Bs[cg + 0][r] = b.x; Bs[cg + 1][r] = b.y; Bs[cg + 2][r] = b.z; Bs[cg + 3][r] = b.w;
        }
        __syncthreads();
#pragma unroll
        for (int kk = 0; kk < 16; ++kk) {
            float4 a0 = *(const float4*)&As[kk][ty * 8];
            float4 a1 = *(const float4*)&As[kk][ty * 8 + 4];
            float4 b0 = *(const float4*)&Bs[kk][tx * 8];
            float4 b1 = *(const float4*)&Bs[kk][tx * 8 + 4];
            float am[8] = {a0.x, a0.y, a0.z, a0.w, a1.x, a1.y, a1.z, a1.w};
            float bn[8] = {b0.x, b0.y, b0.z, b0.w, b1.x, b1.y, b1.z, b1.w};
#pragma unroll
            for (int i2 = 0; i2 < 8; ++i2)
#pragma unroll
                for (int j2 = 0; j2 < 8; ++j2) acc[i2][j2] += am[i2] * bn[j2];
        }
        __syncthreads();
    }

#pragma unroll
    for (int i2 = 0; i2 < 8; ++i2) {
        const int m = m0 + ty * 8 + i2;
#pragma unroll
        for (int jc = 0; jc < 2; ++jc) {
            const int n = n0 + tx * 8 + jc * 4;
            float4 v;
            v.x = acc[i2][jc * 4 + 0] + bias[n + 0];
            v.y = acc[i2][jc * 4 + 1] + bias[n + 1];
            v.z = acc[i2][jc * 4 + 2] + bias[n + 2];
            v.w = acc[i2][jc * 4 + 3] + bias[n + 3];
            if (MODE == 0) {
                const int b = m >> 10, s = m & 1023, h = n >> 6, hd = n & 63;
                *(float4*)&out[((size_t)(b * 16 + h) * 1024 + s) * 64 + hd] = v;
            } else {
                *(float4*)&out[(size_t)m * 1024 + n] = v;
            }
        }
    }
}

// ---------------------------------------------------------------------------
// Attention: per (64-row q tile, h, b).  Pass 1: online max/sum.  Pass 2:
// recompute scores, write softmax probs (268 MB) and accumulate ctx = P @ V.
// ---------------------------------------------------------------------------
__global__ __launch_bounds__(256, 2) void attn_kernel(
    const float* __restrict__ q, const float* __restrict__ k, const float* __restrict__ v,
    float* __restrict__ attn, float* __restrict__ ctx)
{
    const int qt = blockIdx.x, h = blockIdx.y, b = blockIdx.z;
    const float scale = 0.125f;

    const float* qp = q + ((size_t)(b * 16 + h) * 1024 + qt * 64) * 64;
    const float* kp = k + (size_t)(b * 16 + h) * 1024 * 64;
    const float* vp = v + (size_t)(b * 16 + h) * 1024 * 64;

    const int tid = threadIdx.x, tx = tid & 15, ty = tid >> 4;

    __shared__ float qs[64][68];
    __shared__ float ks[64][68];
    __shared__ float vs[64][68];
    __shared__ float ps[64][68];

#pragma unroll
    for (int i = 0; i < 4; ++i) {
        int f = tid + i * 256;
        int r = f >> 4, c = (f & 15) * 4;
        *(float4*)&qs[r][c] = *(const float4*)&qp[r * 64 + c];
    }

    float m[4], l[4];
#pragma unroll
    for (int i = 0; i < 4; ++i) { m[i] = -INFINITY; l[i] = 0.f; }

    // -------- pass 1 --------
    for (int kt = 0; kt < 16; ++kt) {
        __syncthreads();
#pragma unroll
        for (int i = 0; i < 4; ++i) {
            int f = tid + i * 256;
            int r = f >> 4, c = (f & 15) * 4;
            *(float4*)&ks[r][c] = *(const float4*)&kp[(kt * 64 + r) * 64 + c];
        }
        __syncthreads();

        float sc_[4][4] = {};
#pragma unroll
        for (int hc = 0; hc < 16; ++hc) {
            float4 q4[4], k4[4];
#pragma unroll
            for (int i = 0; i < 4; ++i) q4[i] = *(const float4*)&qs[ty * 4 + i][hc * 4];
#pragma unroll
            for (int j = 0; j < 4; ++j) k4[j] = *(const float4*)&ks[tx * 4 + j][hc * 4];
#pragma unroll
            for (int i = 0; i < 4; ++i)
#pragma unroll
                for (int j = 0; j < 4; ++j) sc_[i][j] += dot4(q4[i], k4[j]);
        }
#pragma unroll
        for (int i = 0; i < 4; ++i) {
            float mx = fmaxf(fmaxf(sc_[i][0], sc_[i][1]), fmaxf(sc_[i][2], sc_[i][3])) * scale;
#pragma unroll
            for (int msk = 1; msk < 16; msk <<= 1) mx = fmaxf(mx, __shfl_xor(mx, msk));
            float mn = fmaxf(m[i], mx);
            float add = 0.f;
#pragma unroll
            for (int j = 0; j < 4; ++j) add += __expf(sc_[i][j] * scale - mn);
#pragma unroll
            for (int msk = 1; msk < 16; msk <<= 1) add += __shfl_xor(add, msk);
            l[i] = l[i] * __expf(m[i] - mn) + add;
            m[i] = mn;
        }
    }

    float inv_l[4];
#pragma unroll
    for (int i = 0; i < 4; ++i) inv_l[i] = 1.f / l[i];

    // -------- pass 2 --------
    float cacc[4][4] = {};
    for (int kt = 0; kt < 16; ++kt) {
        __syncthreads();
#pragma unroll
        for (int i = 0; i < 4; ++i) {
            int f = tid + i * 256;
            int r = f >> 4, c = (f & 15) * 4;
            *(float4*)&ks[r][c] = *(const float4*)&kp[(kt * 64 + r) * 64 + c];
            *(float4*)&vs[r][c] = *(const float4*)&vp[(kt * 64 + r) * 64 + c];
        }
        __syncthreads();

        float sc_[4][4] = {};
#pragma unroll
        for (int hc = 0; hc < 16; ++hc) {
            float4 q4[4], k4[4];
#pragma unroll
            for (int i = 0; i < 4; ++i) q4[i] = *(const float4*)&qs[ty * 4 + i][hc * 4];
#pragma unroll
            for (int j = 0; j < 4; ++j) k4[j] = *(const float4*)&ks[tx * 4 + j][hc * 4];
#pragma unroll
            for (int i = 0; i < 4; ++i)
#pragma unroll
                for (int j = 0; j < 4; ++j) sc_[i][j] += dot4(q4[i], k4[j]);
        }
#pragma unroll
        for (int i = 0; i < 4; ++i) {
            const int row = qt * 64 + ty * 4 + i;
            float4 p4;
            p4.x = __expf(sc_[i][0] * scale - m[i]) * inv_l[i];
            p4.y = __expf(sc_[i][1] * scale - m[i]) * inv_l[i];
            p4.z = __expf(sc_[i][2] * scale - m[i]) * inv_l[i];
            p4.w = __expf(sc_[i][3] * scale - m[i]) * inv_l[i];
            *(float4*)&attn[((size_t)(b * 16 + h) * 1024 + row) * 1024 + kt * 64 + tx * 4] = p4;
            *(float4*)&ps[ty * 4 + i][tx * 4] = p4;
        }
        __syncthreads();
#pragma unroll
        for (int kc = 0; kc < 16; ++kc) {
            float4 p4[4], v4[4];
#pragma unroll
            for (int i = 0; i < 4; ++i) p4[i] = *(const float4*)&ps[ty * 4 + i][kc * 4];
#pragma unroll
            for (int j = 0; j < 4; ++j) v4[j] = *(const float4*)&vs[kc * 4 + j][tx * 4];
#pragma unroll
            for (int i = 0; i < 4; ++i) {
                float4 p = p4[i];
                cacc[i][0] += p.x * v4[0].x + p.y * v4[1].x + p.z * v4[2].x + p.w * v4[3].x;
                cacc[i][1] += p.x * v4[0].y + p.y * v4[1].y + p.z * v4[2].y + p.w * v4[3].y;
                cacc[i][2] += p.x * v4[0].z + p.y * v4[1].z + p.z * v4[2].z + p.w * v4[3].z;
                cacc[i][3] += p.x * v4[0].w + p.y * v4[1].w + p.z * v4[2].w + p.w * v4[3].w;
            }
        }
    }

#pragma unroll
    for (int i = 0; i < 4; ++i) {
        const int s = qt * 64 + ty * 4 + i;
        float4 v4o; v4o.x = cacc[i][0]; v4o.y = cacc[i][1]; v4o.z = cacc[i][2]; v4o.w = cacc[i][3];
        *(float4*)&ctx[((size_t)(b * 1024 + s) * 16 + h) * 64 + tx * 4] = v4o;
    }
}

// ---------------------------------------------------------------------------
extern "C" void kernel_launch(void* const* d_in, const int* in_sizes, int n_in,
                              void* d_out, int out_size, void* d_ws, size_t ws_size,
                              hipStream_t stream)
{
    const float* x     = (const float*)d_in[0];
    const int*   tidx  = (const int*)d_in[1];
    const float* alpha = (const float*)d_in[2];
    const float* beta  = (const float*)d_in[3];
    const float* gamma = (const float*)d_in[4];
    const float* seas  = (const float*)d_in[5];
    const float* Wl = (const float*)d_in[6];  const float* bl = (const float*)d_in[7];
    const float* Wt = (const float*)d_in[8];  const float* bt = (const float*)d_in[9];
    const float* Ws = (const float*)d_in[10]; const float* bs = (const float*)d_in[11];
    const float* Wq = (const float*)d_in[12]; const float* bq = (const float*)d_in[13];
    const float* Wk = (const float*)d_in[14]; const float* bk = (const float*)d_in[15];
    const float* Wv = (const float*)d_in[16]; const float* bv = (const float*)d_in[17];
    const float* Wo = (const float*)d_in[18]; const float* bo = (const float*)d_in[19];
    const float* temb = (const float*)d_in[20];

    float* out = (float*)d_out;
    float* ws  = (float*)d_ws;

    float* q_ws   = ws + WS_Q;
    float* k_ws   = ws + WS_K;
    float* v_ws   = ws + WS_V;
    float* ctx_ws = ws + WS_CTX;
    float* btl    = ws + WS_BTL;
    float* bsl    = ws + WS_BSL;
    unsigned* flags = (unsigned*)(ws + WS_FLAGS);

    // M1/M2 parked in the (not-yet-written) attn output region of d_out:
    // read only during scan's register preload, overwritten later by attn_kernel.
    float* M1 = out + OUT_ATTN;
    float* M2 = out + OUT_ATTN + 1048576u;

    // 0) precompute folded weights/biases
    bias_fold<<<16, 256, 0, stream>>>(Wt, bt, Ws, bs, bl, beta, gamma, btl, bsl);
    ww_gemm<<<dim3(16, 16, 2), 256, 0, stream>>>(Wt, Ws, Wl, M1, M2);

    // 1) sequential Holt-Winters scan (1 barrier/step)
    scan_kernel<<<NBLK, 256, 0, stream>>>(
        x, tidx, alpha, beta, gamma, seas,
        Wl, bl, Wt, Ws, M1, M2, btl, bsl,
        out + OUT_HW, out + OUT_LEVEL, out + OUT_TREND,
        ws + WS_LEVEL, ws + WS_TREND, ws + WS_SBUF,
        flags);

    // 2) Q/K/V projections (enhanced = hw + temporal_emb fused into A load)
    gemm_kernel<0><<<dim3(32, 8, 3), 256, 0, stream>>>(
        out + OUT_HW, temb, tidx,
        Wq, bq, Wk, bk, Wv, bv,
        q_ws, k_ws, v_ws);

    // 3) attention: probs -> d_out, ctx -> ws
    attn_kernel<<<dim3(16, 16, 4), 256, 0, stream>>>(
        q_ws, k_ws, v_ws, out + OUT_ATTN, ctx_ws);

    // 4) output projection
    gemm_kernel<1><<<dim3(32, 8, 1), 256, 0, stream>>>(
        ctx_ws, nullptr, nullptr,
        Wo, bo, Wo, bo, Wo, bo,
        out, nullptr, nullptr);
}